// Round 11
// baseline (3931.113 us; speedup 1.0000x reference)
//
#include <hip/hip_runtime.h>

#define NB 4
#define NN 256
#define NH 128
#define LN_EPS 1e-5f

__device__ __forceinline__ float elu1(float x){
  return x > 0.f ? x : (__expf(x) - 1.f);
}

__device__ __forceinline__ void ln_reduce32(float& s, float& s2){
  #pragma unroll
  for (int m = 1; m <= 16; m <<= 1){
    s  += __shfl_xor(s,  m, 64);
    s2 += __shfl_xor(s2, m, 64);
  }
}

// K0a: lin_in = v@W_in.T + b_in ; lin_out = v@W_out.T + b_out (fp32 exact)
__global__ __launch_bounds__(128) void lin_vw_kernel(
    const float* __restrict__ v,
    const float* __restrict__ W_in, const float* __restrict__ b_in,
    const float* __restrict__ W_out, const float* __restrict__ b_out,
    float* __restrict__ lin_in, float* __restrict__ lin_out)
{
  const int row = blockIdx.x;    // b*NN + i
  const int t = threadIdx.x;     // output col
  __shared__ float vs[NH];
  vs[t] = v[(size_t)row*NH + t];
  __syncthreads();
  const float4* wi = (const float4*)(W_in + t*NH);
  const float4* wo = (const float4*)(W_out + t*NH);
  const float4* vv = (const float4*)vs;
  float ai = b_in[t], ao = b_out[t];
  #pragma unroll
  for (int k = 0; k < NH/4; ++k){
    float4 x = vv[k];
    float4 a = wi[k], bq = wo[k];
    ai += x.x*a.x + x.y*a.y + x.z*a.z + x.w*a.w;
    ao += x.x*bq.x + x.y*bq.y + x.z*bq.z + x.w*bq.w;
  }
  lin_in[(size_t)row*NH + t]  = ai;
  lin_out[(size_t)row*NH + t] = ao;
}

// K0b: Wt_g[k][c] = W_e2e[c][k]
__global__ __launch_bounds__(128) void transpose_w_kernel(
    const float* __restrict__ W, float* __restrict__ Wt)
{
  const int c = blockIdx.x;
  const int k = threadIdx.x;
  Wt[(size_t)k*NH + c] = W[(size_t)c*NH + k];
}

#define LD4(p) (*(const float4*)(p))

#define FMA4(a, ev, q0, q1, q2, q3) \
  a.x += ev.x*q0.x + ev.y*q1.x + ev.z*q2.x + ev.w*q3.x; \
  a.y += ev.x*q0.y + ev.y*q1.y + ev.z*q2.y + ev.w*q3.y; \
  a.z += ev.x*q0.z + ev.y*q1.z + ev.z*q2.z + ev.w*q3.z; \
  a.w += ev.x*q0.w + ev.y*q1.w + ev.z*q2.w + ev.w*q3.w;

// Main: one block per (b,j). Thread (it,ic): 4 rows x 4 cols per i0-step,
// 8 steps. Software-pipelined k-loop (prefetch distance 1, all-static regs).
// Fused epilogue: LN->ELU->mask->store out_e + register agg -> LN -> out_v.
__global__ __launch_bounds__(256, 2) void nri_fused_tiled_kernel(
    const float* __restrict__ e,
    const float* __restrict__ v,
    const int* __restrict__ v_mask,
    const int* __restrict__ e_mask,
    const float* __restrict__ Wt_g,  const float* __restrict__ b_e2e,
    const float* __restrict__ g_e,   const float* __restrict__ be_e,
    const float* __restrict__ g_v,   const float* __restrict__ be_v,
    const float* __restrict__ lin_in, const float* __restrict__ lin_out,
    float* __restrict__ out_e, float* __restrict__ out_v)
{
  const int blk = blockIdx.x, b = blk >> 8, j = blk & (NN-1);
  const int tid = threadIdx.x;
  const int it  = tid >> 5;      // 0..7 : row group (4 rows per i0-step)
  const int ic  = tid & 31;      // cols 4ic .. 4ic+3
  const int c0  = 4*ic;
  const int wave = tid >> 6;

  __shared__ float aggl[4][NH];
  __shared__ float red[4];

  float bj[4], gc[4], bec[4];
  {
    const float* lo = lin_out + (size_t)(b*NN + j)*NH + c0;
    #pragma unroll
    for (int cc = 0; cc < 4; ++cc){
      bj[cc]  = lo[cc] + b_e2e[c0+cc];
      gc[cc]  = g_e[c0+cc];
      bec[cc] = be_e[c0+cc];
    }
  }

  float aggacc[4] = {0.f, 0.f, 0.f, 0.f};

  const size_t ebase   = ((size_t)b*NN)*NN*NH + (size_t)j*NH;
  const size_t estride = (size_t)NN*NH;
  const int*   emcol   = e_mask + (size_t)(b*NN)*NN + j;
  const float* wbase   = Wt_g + c0;

  for (int i0 = 0; i0 < NN; i0 += 32){
    const int ibase = i0 + it*4;
    const float* e0 = e + ebase + (size_t)(ibase+0)*estride;
    const float* e1 = e + ebase + (size_t)(ibase+1)*estride;
    const float* e2 = e + ebase + (size_t)(ibase+2)*estride;
    const float* e3 = e + ebase + (size_t)(ibase+3)*estride;

    float4 a0 = {0,0,0,0}, a1 = {0,0,0,0}, a2 = {0,0,0,0}, a3 = {0,0,0,0};

    // prologue: chunk 0 e-rows
    float4 pa0 = LD4(e0), pa1 = LD4(e1), pa2 = LD4(e2), pa3 = LD4(e3);

    #pragma unroll
    for (int kk = 0; kk < 16; ++kk){
      const int k = 8*kk;
      // prefetch chunk k+4 (max 124..127: in-bounds)
      float4 pb0 = LD4(e0 + k + 4), pb1 = LD4(e1 + k + 4);
      float4 pb2 = LD4(e2 + k + 4), pb3 = LD4(e3 + k + 4);
      // W rows k..k+3 (L1/L2-resident)
      float4 wa0 = LD4(wbase + (size_t)(k+0)*NH);
      float4 wa1 = LD4(wbase + (size_t)(k+1)*NH);
      float4 wa2 = LD4(wbase + (size_t)(k+2)*NH);
      float4 wa3 = LD4(wbase + (size_t)(k+3)*NH);
      FMA4(a0, pa0, wa0, wa1, wa2, wa3);
      FMA4(a1, pa1, wa0, wa1, wa2, wa3);
      FMA4(a2, pa2, wa0, wa1, wa2, wa3);
      FMA4(a3, pa3, wa0, wa1, wa2, wa3);
      if (kk < 15){
        pa0 = LD4(e0 + k + 8); pa1 = LD4(e1 + k + 8);
        pa2 = LD4(e2 + k + 8); pa3 = LD4(e3 + k + 8);
      }
      float4 wb0 = LD4(wbase + (size_t)(k+4)*NH);
      float4 wb1 = LD4(wbase + (size_t)(k+5)*NH);
      float4 wb2 = LD4(wbase + (size_t)(k+6)*NH);
      float4 wb3 = LD4(wbase + (size_t)(k+7)*NH);
      FMA4(a0, pb0, wb0, wb1, wb2, wb3);
      FMA4(a1, pb1, wb0, wb1, wb2, wb3);
      FMA4(a2, pb2, wb0, wb1, wb2, wb3);
      FMA4(a3, pb3, wb0, wb1, wb2, wb3);
    }

    // epilogue per row: +lin_in +bias -> LN -> ELU -> mask -> store + agg
    #define EPI(ar, rr_) { \
      const int i = ibase + rr_; \
      const float4 li = LD4(lin_in + (size_t)(b*NN + i)*NH + c0); \
      const float x0 = ar.x + li.x + bj[0]; \
      const float x1 = ar.y + li.y + bj[1]; \
      const float x2 = ar.z + li.z + bj[2]; \
      const float x3 = ar.w + li.w + bj[3]; \
      float s  = x0 + x1 + x2 + x3; \
      float s2 = x0*x0 + x1*x1 + x2*x2 + x3*x3; \
      ln_reduce32(s, s2); \
      const float mu  = s * (1.f/NH); \
      const float var = s2 * (1.f/NH) - mu*mu; \
      const float rs  = rsqrtf(var + LN_EPS); \
      const int zf = (i == j) || emcol[(size_t)i*NN]; \
      float4 hh; \
      hh.x = zf ? 0.f : elu1((x0 - mu)*rs*gc[0] + bec[0]); \
      hh.y = zf ? 0.f : elu1((x1 - mu)*rs*gc[1] + bec[1]); \
      hh.z = zf ? 0.f : elu1((x2 - mu)*rs*gc[2] + bec[2]); \
      hh.w = zf ? 0.f : elu1((x3 - mu)*rs*gc[3] + bec[3]); \
      *(float4*)(out_e + ebase + (size_t)i*estride + c0) = hh; \
      aggacc[0] += hh.x; aggacc[1] += hh.y; \
      aggacc[2] += hh.z; aggacc[3] += hh.w; }

    EPI(a0, 0)
    EPI(a1, 1)
    EPI(a2, 2)
    EPI(a3, 3)
    #undef EPI
  }

  // ---- fused out_v ----
  #pragma unroll
  for (int cc = 0; cc < 4; ++cc)
    aggacc[cc] += __shfl_xor(aggacc[cc], 32, 64);   // combine it-pair in wave
  if ((tid & 63) < 32){
    #pragma unroll
    for (int cc = 0; cc < 4; ++cc) aggl[wave][c0+cc] = aggacc[cc];
  }
  __syncthreads();

  float a = 0.f, s = 0.f, s2 = 0.f;
  if (tid < NH){
    const int c = tid;
    a = aggl[0][c] + aggl[1][c] + aggl[2][c] + aggl[3][c];
    s = a; s2 = a*a;
    #pragma unroll
    for (int m = 1; m <= 32; m <<= 1){
      s  += __shfl_xor(s,  m, 64);
      s2 += __shfl_xor(s2, m, 64);
    }
  }
  if (tid < NH && (tid & 63) == 0){
    red[(tid>>6)*2] = s; red[(tid>>6)*2 + 1] = s2;
  }
  __syncthreads();
  if (tid < NH){
    const int c = tid;
    const float S  = red[0] + red[2];
    const float S2 = red[1] + red[3];
    const float mu  = S * (1.f/NH);
    const float var = S2 * (1.f/NH) - mu*mu;
    const float rs  = rsqrtf(var + LN_EPS);
    const float h   = elu1((a - mu)*rs*g_v[c] + be_v[c]);
    const int vm = v_mask[b*NN + j];
    const float vv = vm ? 0.f : v[(size_t)(b*NN + j)*NH + c];
    out_v[(size_t)(b*NN + j)*NH + c] = vv + h;
  }
}

extern "C" void kernel_launch(void* const* d_in, const int* in_sizes, int n_in,
                              void* d_out, int out_size, void* d_ws, size_t ws_size,
                              hipStream_t stream)
{
  const float* v      = (const float*)d_in[0];
  const float* e      = (const float*)d_in[1];
  const int*   v_mask = (const int*)d_in[2];
  const int*   e_mask = (const int*)d_in[3];
  const float* W_in   = (const float*)d_in[4];
  const float* b_in   = (const float*)d_in[5];
  const float* W_out  = (const float*)d_in[6];
  const float* b_out  = (const float*)d_in[7];
  const float* W_e2e  = (const float*)d_in[8];
  const float* b_e2e  = (const float*)d_in[9];
  const float* g_e    = (const float*)d_in[10];
  const float* be_e   = (const float*)d_in[11];
  const float* g_v    = (const float*)d_in[12];
  const float* be_v   = (const float*)d_in[13];

  float* lin_in  = (float*)d_ws;                 // [NB*NN, NH]
  float* lin_out = lin_in + NB*NN*NH;            // [NB*NN, NH]
  float* Wt_g    = lin_out + NB*NN*NH;           // [NH, NH]
  float* out_v = (float*)d_out;                  // [NB,NN,NH]
  float* out_e = out_v + (size_t)NB*NN*NH;       // [NB,NN,NN,NH]

  lin_vw_kernel<<<NB*NN, NH, 0, stream>>>(v, W_in, b_in, W_out, b_out,
                                          lin_in, lin_out);
  transpose_w_kernel<<<NH, NH, 0, stream>>>(W_e2e, Wt_g);
  nri_fused_tiled_kernel<<<NB*NN, 256, 0, stream>>>(e, v, v_mask, e_mask,
                                                    Wt_g, b_e2e, g_e, be_e,
                                                    g_v, be_v,
                                                    lin_in, lin_out,
                                                    out_e, out_v);
}

// Round 12
// 248.399 us; speedup vs baseline: 15.8258x; 15.8258x over previous
//
#include <hip/hip_runtime.h>

#define NB 4
#define NN 256
#define NH 128
#define LN_EPS 1e-5f

__device__ __forceinline__ float elu1(float x){
  return x > 0.f ? x : (__expf(x) - 1.f);
}

// K0a: lin_in = v@W_in.T + b_in ; lin_out = v@W_out.T + b_out (fp32 exact)
__global__ __launch_bounds__(128) void lin_vw_kernel(
    const float* __restrict__ v,
    const float* __restrict__ W_in, const float* __restrict__ b_in,
    const float* __restrict__ W_out, const float* __restrict__ b_out,
    float* __restrict__ lin_in, float* __restrict__ lin_out)
{
  const int row = blockIdx.x;    // b*NN + i
  const int t = threadIdx.x;     // output col
  __shared__ float vs[NH];
  vs[t] = v[(size_t)row*NH + t];
  __syncthreads();
  const float4* wi = (const float4*)(W_in + t*NH);
  const float4* wo = (const float4*)(W_out + t*NH);
  const float4* vv = (const float4*)vs;
  float ai = b_in[t], ao = b_out[t];
  #pragma unroll
  for (int k = 0; k < NH/4; ++k){
    float4 x = vv[k];
    float4 a = wi[k], bq = wo[k];
    ai += x.x*a.x + x.y*a.y + x.z*a.z + x.w*a.w;
    ao += x.x*bq.x + x.y*bq.y + x.z*bq.z + x.w*bq.w;
  }
  lin_in[(size_t)row*NH + t]  = ai;
  lin_out[(size_t)row*NH + t] = ao;
}

// K0b: Wt_g[k][c] = W_e2e[c][k]
__global__ __launch_bounds__(128) void transpose_w_kernel(
    const float* __restrict__ W, float* __restrict__ Wt)
{
  const int c = blockIdx.x;
  const int k = threadIdx.x;
  Wt[(size_t)k*NH + c] = W[(size_t)c*NH + k];
}

#define LD4(p) (*(const float4*)(p))

// Main: one block per (b,j), 4 waves. Tile = 32 i-rows staged in LDS.
// Async-split staging (T14): issue next tile's coalesced loads -> compute
// current tile from LDS (broadcast ds_read_b128) -> barrier -> ds_write.
// Lane owns 2 cols x 8 rows; W from pre-transposed global (coalesced, L1).
// Fused epilogue: LN->ELU->mask->out_e + register agg -> LN -> out_v.
__global__ __launch_bounds__(256) void nri_fused_tiled_kernel(
    const float* __restrict__ e,
    const float* __restrict__ v,
    const int* __restrict__ v_mask,
    const int* __restrict__ e_mask,
    const float* __restrict__ Wt_g,  const float* __restrict__ b_e2e,
    const float* __restrict__ g_e,   const float* __restrict__ be_e,
    const float* __restrict__ g_v,   const float* __restrict__ be_v,
    const float* __restrict__ lin_in, const float* __restrict__ lin_out,
    float* __restrict__ out_e, float* __restrict__ out_v)
{
  const int blk  = blockIdx.x, b = blk >> 8, j = blk & (NN-1);
  const int tid  = threadIdx.x;
  const int wave = tid >> 6;
  const int l    = tid & 63;
  const int c0   = 2*l;          // this lane's 2 columns

  __shared__ float etile[32][NH];   // 16 KB e tile (single buffer, 2 barriers)
  __shared__ float aggl[4][NH];     // per-wave agg partials
  __shared__ float red[4];

  // per-lane column constants
  const float* lo = lin_out + (size_t)(b*NN + j)*NH;
  const float bj0  = lo[c0]   + b_e2e[c0];
  const float bj1  = lo[c0+1] + b_e2e[c0+1];
  const float gc0  = g_e[c0],  gc1  = g_e[c0+1];
  const float bec0 = be_e[c0], bec1 = be_e[c0+1];

  float agg0 = 0.f, agg1 = 0.f;

  const size_t ebase   = ((size_t)b*NN)*NN*NH + (size_t)j*NH;
  const size_t estride = (size_t)NN*NH;
  const int*   emcol   = e_mask + (size_t)(b*NN)*NN + j;

  // staging: wave w owns tile rows 8w..8w+7; lane covers 2 rows/step, 16B each
  const int srow  = 8*wave;
  const int scol  = (l & 31) * 4;  // float index within row
  const int shalf = l >> 5;        // 0/1: which row of the pair
  float4 st0, st1, st2, st3;

  #define STAGE_LOAD(i0_) { \
    const float* sb = e + ebase + scol; \
    st0 = LD4(sb + (size_t)((i0_) + srow + 0 + shalf)*estride); \
    st1 = LD4(sb + (size_t)((i0_) + srow + 2 + shalf)*estride); \
    st2 = LD4(sb + (size_t)((i0_) + srow + 4 + shalf)*estride); \
    st3 = LD4(sb + (size_t)((i0_) + srow + 6 + shalf)*estride); }

  #define STAGE_WRITE() { \
    *(float4*)&etile[srow + 0 + shalf][scol] = st0; \
    *(float4*)&etile[srow + 2 + shalf][scol] = st1; \
    *(float4*)&etile[srow + 4 + shalf][scol] = st2; \
    *(float4*)&etile[srow + 6 + shalf][scol] = st3; }

  STAGE_LOAD(0)
  STAGE_WRITE()
  __syncthreads();

  for (int t = 0; t < 8; ++t){
    const int i0 = 32*t;
    if (t < 7) STAGE_LOAD(i0 + 32)   // in flight across the whole compute phase

    // ---- compute 8 rows x 2 cols from LDS ----
    float2 acc[8];
    #pragma unroll
    for (int r = 0; r < 8; ++r) acc[r] = make_float2(0.f, 0.f);

    for (int k = 0; k < NH; k += 4){
      const float2 w0 = *(const float2*)(Wt_g + (size_t)(k+0)*NH + c0);
      const float2 w1 = *(const float2*)(Wt_g + (size_t)(k+1)*NH + c0);
      const float2 w2 = *(const float2*)(Wt_g + (size_t)(k+2)*NH + c0);
      const float2 w3 = *(const float2*)(Wt_g + (size_t)(k+3)*NH + c0);
      #pragma unroll
      for (int r = 0; r < 8; ++r){
        const float4 ev = *(const float4*)&etile[srow + r][k];  // broadcast
        acc[r].x += ev.x*w0.x + ev.y*w1.x + ev.z*w2.x + ev.w*w3.x;
        acc[r].y += ev.x*w0.y + ev.y*w1.y + ev.z*w2.y + ev.w*w3.y;
      }
    }

    // ---- epilogue per row: +lin_in +bias -> LN -> ELU -> mask -> store + agg
    #pragma unroll
    for (int r = 0; r < 8; ++r){
      const int i = i0 + srow + r;
      const float2 li = *(const float2*)(lin_in + (size_t)(b*NN + i)*NH + c0);
      const float x0 = acc[r].x + li.x + bj0;
      const float x1 = acc[r].y + li.y + bj1;
      float s  = x0 + x1;
      float s2 = x0*x0 + x1*x1;
      #pragma unroll
      for (int m = 1; m <= 32; m <<= 1){
        s  += __shfl_xor(s,  m, 64);
        s2 += __shfl_xor(s2, m, 64);
      }
      const float mu  = s * (1.f/NH);
      const float var = s2 * (1.f/NH) - mu*mu;
      const float rs  = rsqrtf(var + LN_EPS);
      const int zf = (i == j) || emcol[(size_t)i*NN];
      float2 hh;
      hh.x = zf ? 0.f : elu1((x0 - mu)*rs*gc0 + bec0);
      hh.y = zf ? 0.f : elu1((x1 - mu)*rs*gc1 + bec1);
      *(float2*)(out_e + ebase + (size_t)i*estride + c0) = hh;
      agg0 += hh.x; agg1 += hh.y;
    }

    __syncthreads();                 // all reads of etile done
    if (t < 7){ STAGE_WRITE() }
    __syncthreads();                 // staged rows visible
  }

  // ---- fused out_v ----
  aggl[wave][c0]   = agg0;
  aggl[wave][c0+1] = agg1;
  __syncthreads();

  float a = 0.f, s = 0.f, s2 = 0.f;
  if (tid < NH){
    const int c = tid;
    a = aggl[0][c] + aggl[1][c] + aggl[2][c] + aggl[3][c];
    s = a; s2 = a*a;
    #pragma unroll
    for (int m = 1; m <= 32; m <<= 1){
      s  += __shfl_xor(s,  m, 64);
      s2 += __shfl_xor(s2, m, 64);
    }
  }
  if (tid < NH && (tid & 63) == 0){
    red[(tid>>6)*2] = s; red[(tid>>6)*2 + 1] = s2;
  }
  __syncthreads();
  if (tid < NH){
    const int c = tid;
    const float S  = red[0] + red[2];
    const float S2 = red[1] + red[3];
    const float mu  = S * (1.f/NH);
    const float var = S2 * (1.f/NH) - mu*mu;
    const float rs  = rsqrtf(var + LN_EPS);
    const float h   = elu1((a - mu)*rs*g_v[c] + be_v[c]);
    const int vm = v_mask[b*NN + j];
    const float vv = vm ? 0.f : v[(size_t)(b*NN + j)*NH + c];
    out_v[(size_t)(b*NN + j)*NH + c] = vv + h;
  }
}

extern "C" void kernel_launch(void* const* d_in, const int* in_sizes, int n_in,
                              void* d_out, int out_size, void* d_ws, size_t ws_size,
                              hipStream_t stream)
{
  const float* v      = (const float*)d_in[0];
  const float* e      = (const float*)d_in[1];
  const int*   v_mask = (const int*)d_in[2];
  const int*   e_mask = (const int*)d_in[3];
  const float* W_in   = (const float*)d_in[4];
  const float* b_in   = (const float*)d_in[5];
  const float* W_out  = (const float*)d_in[6];
  const float* b_out  = (const float*)d_in[7];
  const float* W_e2e  = (const float*)d_in[8];
  const float* b_e2e  = (const float*)d_in[9];
  const float* g_e    = (const float*)d_in[10];
  const float* be_e   = (const float*)d_in[11];
  const float* g_v    = (const float*)d_in[12];
  const float* be_v   = (const float*)d_in[13];

  float* lin_in  = (float*)d_ws;                 // [NB*NN, NH]
  float* lin_out = lin_in + NB*NN*NH;            // [NB*NN, NH]
  float* Wt_g    = lin_out + NB*NN*NH;           // [NH, NH]
  float* out_v = (float*)d_out;                  // [NB,NN,NH]
  float* out_e = out_v + (size_t)NB*NN*NH;       // [NB,NN,NN,NH]

  lin_vw_kernel<<<NB*NN, NH, 0, stream>>>(v, W_in, b_in, W_out, b_out,
                                          lin_in, lin_out);
  transpose_w_kernel<<<NH, NH, 0, stream>>>(W_e2e, Wt_g);
  nri_fused_tiled_kernel<<<NB*NN, 256, 0, stream>>>(e, v, v_mask, e_mask,
                                                    Wt_g, b_e2e, g_e, be_e,
                                                    g_v, be_v,
                                                    lin_in, lin_out,
                                                    out_e, out_v);
}

// Round 14
// 236.537 us; speedup vs baseline: 16.6195x; 1.0501x over previous
//
#include <hip/hip_runtime.h>

#define NB 4
#define NN 256
#define NH 128
#define LN_EPS 1e-5f

typedef float f32x2 __attribute__((ext_vector_type(2)));

__device__ __forceinline__ float elu1(float x){
  return x > 0.f ? x : (__expf(x) - 1.f);
}

// K0a: lin_in = v@W_in.T + b_in ; lin_out = v@W_out.T + b_out (fp32 exact).
// Also zeroes out_v (used as the agg accumulator by the main kernel).
__global__ __launch_bounds__(128) void lin_vw_kernel(
    const float* __restrict__ v,
    const float* __restrict__ W_in, const float* __restrict__ b_in,
    const float* __restrict__ W_out, const float* __restrict__ b_out,
    float* __restrict__ lin_in, float* __restrict__ lin_out,
    float* __restrict__ out_v)
{
  const int row = blockIdx.x;    // b*NN + i
  const int t = threadIdx.x;     // output col
  __shared__ float vs[NH];
  vs[t] = v[(size_t)row*NH + t];
  out_v[(size_t)row*NH + t] = 0.f;   // zero agg accumulator
  __syncthreads();
  const float4* wi = (const float4*)(W_in + t*NH);
  const float4* wo = (const float4*)(W_out + t*NH);
  const float4* vv = (const float4*)vs;
  float ai = b_in[t], ao = b_out[t];
  #pragma unroll
  for (int k = 0; k < NH/4; ++k){
    float4 x = vv[k];
    float4 a = wi[k], bq = wo[k];
    ai += x.x*a.x + x.y*a.y + x.z*a.z + x.w*a.w;
    ao += x.x*bq.x + x.y*bq.y + x.z*bq.z + x.w*bq.w;
  }
  lin_in[(size_t)row*NH + t]  = ai;
  lin_out[(size_t)row*NH + t] = ao;
}

// K0b: Wt_g[k][c] = W_e2e[c][k]
__global__ __launch_bounds__(128) void transpose_w_kernel(
    const float* __restrict__ W, float* __restrict__ Wt)
{
  const int c = blockIdx.x;
  const int k = threadIdx.x;
  Wt[(size_t)k*NH + c] = W[(size_t)c*NH + k];
}

#define LD4(p) (*(const float4*)(p))

// Main: grid = 2048; block (half, b, j) handles i in [half*128, half*128+128).
// LDS-staged e tile (async split), lane = 2 cols, f32x2 acc (v_pk_fma_f32).
// Writes e_out; atomicAdds 128 agg partials into out_v (zeroed by K0a).
__global__ __launch_bounds__(256) void nri_eout_kernel(
    const float* __restrict__ e,
    const int* __restrict__ e_mask,
    const float* __restrict__ Wt_g,  const float* __restrict__ b_e2e,
    const float* __restrict__ g_e,   const float* __restrict__ be_e,
    const float* __restrict__ lin_in, const float* __restrict__ lin_out,
    float* __restrict__ out_e, float* __restrict__ out_v)
{
  const int blk  = blockIdx.x;
  const int half = blk >> 10;          // 0 or 1
  const int bj   = blk & 1023;
  const int b    = bj >> 8, j = bj & (NN-1);
  const int ibeg = half * 128;
  const int tid  = threadIdx.x;
  const int wave = tid >> 6;
  const int l    = tid & 63;
  const int c0   = 2*l;

  __shared__ float etile[32][NH];   // 16 KB
  __shared__ float aggl[4][NH];     // 2 KB

  const float* lo = lin_out + (size_t)(b*NN + j)*NH;
  f32x2 bj2, gc2, bec2;
  bj2.x  = lo[c0]   + b_e2e[c0];
  bj2.y  = lo[c0+1] + b_e2e[c0+1];
  gc2.x  = g_e[c0];  gc2.y  = g_e[c0+1];
  bec2.x = be_e[c0]; bec2.y = be_e[c0+1];

  f32x2 agg = {0.f, 0.f};

  const size_t ebase   = ((size_t)b*NN)*NN*NH + (size_t)j*NH;
  const size_t estride = (size_t)NN*NH;
  const int*   emcol   = e_mask + (size_t)(b*NN)*NN + j;

  const int srow  = 8*wave;
  const int scol  = (l & 31) * 4;
  const int shalf = l >> 5;
  float4 st0, st1, st2, st3;

  #define STAGE_LOAD(i0_) { \
    const float* sb = e + ebase + scol; \
    st0 = LD4(sb + (size_t)((i0_) + srow + 0 + shalf)*estride); \
    st1 = LD4(sb + (size_t)((i0_) + srow + 2 + shalf)*estride); \
    st2 = LD4(sb + (size_t)((i0_) + srow + 4 + shalf)*estride); \
    st3 = LD4(sb + (size_t)((i0_) + srow + 6 + shalf)*estride); }

  #define STAGE_WRITE() { \
    *(float4*)&etile[srow + 0 + shalf][scol] = st0; \
    *(float4*)&etile[srow + 2 + shalf][scol] = st1; \
    *(float4*)&etile[srow + 4 + shalf][scol] = st2; \
    *(float4*)&etile[srow + 6 + shalf][scol] = st3; }

  STAGE_LOAD(ibeg)
  STAGE_WRITE()
  __syncthreads();

  for (int t = 0; t < 4; ++t){
    const int i0 = ibeg + 32*t;
    if (t < 3) STAGE_LOAD(i0 + 32)   // in flight across the compute phase

    f32x2 acc[8];
    #pragma unroll
    for (int r = 0; r < 8; ++r) acc[r] = (f32x2){0.f, 0.f};

    for (int k = 0; k < NH; k += 4){
      const f32x2 w0 = *(const f32x2*)(Wt_g + (size_t)(k+0)*NH + c0);
      const f32x2 w1 = *(const f32x2*)(Wt_g + (size_t)(k+1)*NH + c0);
      const f32x2 w2 = *(const f32x2*)(Wt_g + (size_t)(k+2)*NH + c0);
      const f32x2 w3 = *(const f32x2*)(Wt_g + (size_t)(k+3)*NH + c0);
      #pragma unroll
      for (int r = 0; r < 8; ++r){
        const float4 ev = *(const float4*)&etile[srow + r][k];  // broadcast
        acc[r] += w0*ev.x + w1*ev.y + w2*ev.z + w3*ev.w;        // v_pk_fma_f32
      }
    }

    #pragma unroll
    for (int r = 0; r < 8; ++r){
      const int i = i0 + srow + r;
      const f32x2 li = *(const f32x2*)(lin_in + (size_t)(b*NN + i)*NH + c0);
      const f32x2 x = acc[r] + li + bj2;
      float s  = x.x + x.y;
      float s2 = x.x*x.x + x.y*x.y;
      #pragma unroll
      for (int m = 1; m <= 32; m <<= 1){
        s  += __shfl_xor(s,  m, 64);
        s2 += __shfl_xor(s2, m, 64);
      }
      const float mu  = s * (1.f/NH);
      const float var = s2 * (1.f/NH) - mu*mu;
      const float rs  = rsqrtf(var + LN_EPS);
      const int zf = (i == j) || emcol[(size_t)i*NN];
      f32x2 hh;
      hh.x = zf ? 0.f : elu1((x.x - mu)*rs*gc2.x + bec2.x);
      hh.y = zf ? 0.f : elu1((x.y - mu)*rs*gc2.y + bec2.y);
      *(f32x2*)(out_e + ebase + (size_t)i*estride + c0) = hh;
      agg += hh;
    }

    __syncthreads();
    if (t < 3){ STAGE_WRITE() }
    __syncthreads();
  }

  // block partial agg -> atomicAdd into out_v (zero-initialized by K0a)
  aggl[wave][c0]   = agg.x;
  aggl[wave][c0+1] = agg.y;
  __syncthreads();
  if (tid < NH){
    const float a = aggl[0][tid] + aggl[1][tid] + aggl[2][tid] + aggl[3][tid];
    atomicAdd(&out_v[(size_t)bj*NH + tid], a);
  }
}

// Combine (in place): out_v currently holds agg; finalize to
// out_v = masked v + elu(LN(agg)).
__global__ __launch_bounds__(128) void vnew_combine_kernel(
    const float* __restrict__ v,
    const int* __restrict__ v_mask,
    const float* __restrict__ g_v, const float* __restrict__ be_v,
    float* __restrict__ out_v)
{
  const int bj = blockIdx.x;   // b*NN + j
  const int c  = threadIdx.x;  // 0..127

  const float a = out_v[(size_t)bj*NH + c];

  __shared__ float red[4];
  float s = a, s2 = a*a;
  #pragma unroll
  for (int m = 1; m <= 32; m <<= 1){
    s  += __shfl_xor(s,  m, 64);
    s2 += __shfl_xor(s2, m, 64);
  }
  const int w = c >> 6;
  if ((c & 63) == 0){ red[w*2] = s; red[w*2+1] = s2; }
  __syncthreads();
  s  = red[0] + red[2];
  s2 = red[1] + red[3];

  const float mu  = s * (1.f/NH);
  const float var = s2 * (1.f/NH) - mu*mu;
  const float rs  = rsqrtf(var + LN_EPS);
  const float h   = elu1((a - mu)*rs*g_v[c] + be_v[c]);
  const int vm = v_mask[bj];
  const float vv = vm ? 0.f : v[(size_t)bj*NH + c];
  out_v[(size_t)bj*NH + c] = vv + h;
}

extern "C" void kernel_launch(void* const* d_in, const int* in_sizes, int n_in,
                              void* d_out, int out_size, void* d_ws, size_t ws_size,
                              hipStream_t stream)
{
  const float* v      = (const float*)d_in[0];
  const float* e      = (const float*)d_in[1];
  const int*   v_mask = (const int*)d_in[2];
  const int*   e_mask = (const int*)d_in[3];
  const float* W_in   = (const float*)d_in[4];
  const float* b_in   = (const float*)d_in[5];
  const float* W_out  = (const float*)d_in[6];
  const float* b_out  = (const float*)d_in[7];
  const float* W_e2e  = (const float*)d_in[8];
  const float* b_e2e  = (const float*)d_in[9];
  const float* g_e    = (const float*)d_in[10];
  const float* be_e   = (const float*)d_in[11];
  const float* g_v    = (const float*)d_in[12];
  const float* be_v   = (const float*)d_in[13];

  // ws layout: byte-identical to the round-12 proven-safe footprint.
  float* lin_in  = (float*)d_ws;                 // [NB*NN, NH]  512 KB
  float* lin_out = lin_in + NB*NN*NH;            // [NB*NN, NH]  512 KB
  float* Wt_g    = lin_out + NB*NN*NH;           // [NH, NH]      64 KB

  float* out_v = (float*)d_out;                  // [NB,NN,NH]
  float* out_e = out_v + (size_t)NB*NN*NH;       // [NB,NN,NN,NH]

  lin_vw_kernel<<<NB*NN, NH, 0, stream>>>(v, W_in, b_in, W_out, b_out,
                                          lin_in, lin_out, out_v);
  transpose_w_kernel<<<NH, NH, 0, stream>>>(W_e2e, Wt_g);
  nri_eout_kernel<<<2*NB*NN, 256, 0, stream>>>(e, e_mask,
                                               Wt_g, b_e2e, g_e, be_e,
                                               lin_in, lin_out,
                                               out_e, out_v);
  vnew_combine_kernel<<<NB*NN, 128, 0, stream>>>(v, v_mask, g_v, be_v, out_v);
}